// Round 1
// 1890.518 us; speedup vs baseline: 1.0846x; 1.0846x over previous
//
#include <hip/hip_runtime.h>
#include <hip/hip_bf16.h>
#include <math.h>

#define B   128
#define NN  36
#define FF  2048
#define AA  1024
#define EE  1024
#define DD  1024
#define VV  10000
#define LL  20
#define TT  19

typedef __attribute__((ext_vector_type(8))) short short8;
typedef __attribute__((ext_vector_type(4))) float floatx4;

// ---------------- sort (stable descending by length) ----------------
__global__ __launch_bounds__(B) void sort_kernel(const int* __restrict__ cap_len,
                                                 int* __restrict__ sort_ind,
                                                 int* __restrict__ dec_len) {
    __shared__ int lsh[B];
    int i = threadIdx.x;
    lsh[i] = cap_len[i];
    __syncthreads();
    int li = lsh[i];
    int rank = 0;
    for (int j = 0; j < B; ++j) {
        int lj = lsh[j];
        rank += (lj > li) || (lj == li && j < i);   // stable descending
    }
    sort_ind[rank] = i;
    dec_len[rank]  = li - 1;
}

// ---------------- fp32 -> bf16 convert ----------------
__global__ void convert_kernel(const float* __restrict__ src,
                               __hip_bfloat16* __restrict__ dst, int n) {
    int i = blockIdx.x * 256 + threadIdx.x;
    if (i < n) dst[i] = __float2bfloat16(src[i]);
}

// ---------------- pack [W1_ih | W1_hh] -> bf16 (4096 x 5120) ----------------
__global__ void pack_w1_kernel(const float* __restrict__ Wih,
                               const float* __restrict__ Whh,
                               __hip_bfloat16* __restrict__ dst) {
    int i = blockIdx.x * 256 + threadIdx.x;
    int n = i / 5120, k = i % 5120;
    float v = (k < 4096) ? Wih[(size_t)n * 4096 + k] : Whh[(size_t)n * 1024 + (k - 4096)];
    dst[i] = __float2bfloat16(v);
}

// ---------------- pack [W2_ih | W2_hh] -> bf16 (4096 x 4096) ----------------
__global__ void pack_w2_kernel(const float* __restrict__ Wih,
                               const float* __restrict__ Whh,
                               __hip_bfloat16* __restrict__ dst) {
    int i = blockIdx.x * 256 + threadIdx.x;
    int n = i >> 12, k = i & 4095;
    float v = (k < 3072) ? Wih[(size_t)n * 3072 + k] : Whh[(size_t)n * 1024 + (k - 3072)];
    dst[i] = __float2bfloat16(v);
}

// ---------------- sorted feats -> bf16 ----------------
__global__ void feats_bf_kernel(const float* __restrict__ img,
                                const int* __restrict__ sort_ind,
                                __hip_bfloat16* __restrict__ dst) {
    int i = blockIdx.x * 256 + threadIdx.x;
    int b = i / (NN * FF);
    int r = i % (NN * FF);
    dst[i] = __float2bfloat16(img[(size_t)sort_ind[b] * (NN * FF) + r]);
}

// ---------------- feats_mean -> x1full slot [1024..3072) ----------------
__global__ void fm_kernel(const float* __restrict__ img,
                          const int* __restrict__ sort_ind,
                          __hip_bfloat16* __restrict__ x1full) {
    int i = blockIdx.x * 256 + threadIdx.x;
    int b = i >> 11;
    int f = i & 2047;
    const float* src = img + (size_t)sort_ind[b] * (NN * FF) + f;
    float s = 0.f;
#pragma unroll
    for (int n = 0; n < NN; ++n) s += src[n * FF];
    x1full[(size_t)b * 5120 + 1024 + f] = __float2bfloat16(s * (1.0f / NN));
}

// ---------------- emb gather (t=0 only; later steps fused into lstm2) ----------------
__global__ void emb_gather_kernel(const float* __restrict__ emb,
                                  const int* __restrict__ caps,
                                  const int* __restrict__ sort_ind,
                                  int t,
                                  __hip_bfloat16* __restrict__ x1full) {
    int i = blockIdx.x * 256 + threadIdx.x;
    int b = i >> 10;
    int e = i & 1023;
    int cap = caps[sort_ind[b] * LL + t];
    x1full[(size_t)b * 5120 + 3072 + e] = __float2bfloat16(emb[(size_t)cap * EE + e]);
}

// ---------------- bf16 MFMA GEMM core ----------------
// EPI=0: fp32 partial at C. EPI=1: preds epilogue (bias+mask+N guard).
// EPI=2: bf16 output (att1).
#define BM 128
#define BN 64
#define BK 64
#define LDS_K 72

template<int EPI>
__device__ __forceinline__ void gemm_core(
        short (*As)[LDS_K], short (*Wsm)[LDS_K],
        int bm, int bn, int k0,
        const __hip_bfloat16* __restrict__ A, int lda,
        const __hip_bfloat16* __restrict__ W, int ldw,
        float* __restrict__ C, int ldc,
        int N, int Kc,
        const float* __restrict__ bias,
        const int* __restrict__ dec_len, int tstep) {
    const int tid  = threadIdx.x;
    const int lane = tid & 63;
    const int wv   = tid >> 6;
    const int quad = lane >> 4;
    const int l15  = lane & 15;
    const int wm   = (wv >> 1) * 64;
    const int wn   = (wv & 1) * 32;
    const int srow = tid >> 3;
    const int scol = (tid & 7) * 8;

    floatx4 acc[4][2];
#pragma unroll
    for (int i = 0; i < 4; ++i)
#pragma unroll
        for (int j = 0; j < 2; ++j)
            acc[i][j] = (floatx4){0.f, 0.f, 0.f, 0.f};

    const __hip_bfloat16* Aptr = A + (size_t)(bm + srow) * lda + k0 + scol;
    const __hip_bfloat16* Wptr = W + k0 + scol;

    for (int kt = 0; kt < Kc; kt += BK) {
#pragma unroll
        for (int p = 0; p < 4; ++p) {
            floatx4 v = *(const floatx4*)(Aptr + (size_t)(p * 32) * lda + kt);
            *(floatx4*)(&As[p * 32 + srow][scol]) = v;
        }
#pragma unroll
        for (int p = 0; p < 2; ++p) {
            int gw = bn + p * 32 + srow;
            floatx4 v;
            if (EPI != 1 || gw < N)
                v = *(const floatx4*)(Wptr + (size_t)gw * ldw + kt);
            else
                v = (floatx4){0.f, 0.f, 0.f, 0.f};
            *(floatx4*)(&Wsm[p * 32 + srow][scol]) = v;
        }
        __syncthreads();
#pragma unroll
        for (int ks = 0; ks < 2; ++ks) {
            short8 af[4], bw[2];
#pragma unroll
            for (int i = 0; i < 4; ++i)
                af[i] = *(const short8*)(&As[wm + i * 16 + l15][ks * 32 + quad * 8]);
#pragma unroll
            for (int j = 0; j < 2; ++j)
                bw[j] = *(const short8*)(&Wsm[wn + j * 16 + l15][ks * 32 + quad * 8]);
#pragma unroll
            for (int i = 0; i < 4; ++i)
#pragma unroll
                for (int j = 0; j < 2; ++j)
                    acc[i][j] = __builtin_amdgcn_mfma_f32_16x16x32_bf16(
                        af[i], bw[j], acc[i][j], 0, 0, 0);
        }
        __syncthreads();
    }

    // D layout: row = quad*4+reg, col = lane&15 (m89-verified)
#pragma unroll
    for (int i = 0; i < 4; ++i) {
        int m = bm + wm + i * 16 + quad * 4;
#pragma unroll
        for (int j = 0; j < 2; ++j) {
            int n = bn + wn + j * 16 + l15;
            if (EPI == 1 && n >= N) continue;
#pragma unroll
            for (int r = 0; r < 4; ++r) {
                float v = acc[i][j][r];
                if (EPI == 1) {
                    bool act = tstep < dec_len[m + r];
                    v = act ? (v + bias[n]) : 0.f;
                    C[(size_t)(m + r) * ldc + n] = v;
                } else if (EPI == 2) {
                    ((__hip_bfloat16*)C)[(size_t)(m + r) * ldc + n] = __float2bfloat16(v);
                } else {
                    C[(size_t)(m + r) * ldc + n] = v;
                }
            }
        }
    }
}

// ---------------- standalone GEMM wrapper ----------------
template<int EPI>
__global__ __launch_bounds__(256) void gemm_bf16(
        const __hip_bfloat16* __restrict__ A, int lda,
        const __hip_bfloat16* __restrict__ W, int ldw,
        float* __restrict__ C, int ldc, size_t pstride,
        int N, int Kc,
        const float* __restrict__ bias,
        const int* __restrict__ dec_len, int tstep) {
    __shared__ __align__(16) short As[BM][LDS_K];
    __shared__ __align__(16) short Wsm[BN][LDS_K];
    gemm_core<EPI>(As, Wsm, blockIdx.y * BM, blockIdx.x * BN, blockIdx.z * Kc,
                   A, lda, W, ldw, C + (size_t)blockIdx.z * pstride, ldc,
                   N, Kc, bias, dec_len, tstep);
}

// ---------------- dual launch: g1(t) split-K (blocks 0..511) + preds(t-1) (blocks 512..668) ----
// preds is off the recurrence critical path; running it inside the same dispatch as
// the next step's g1 hides it on CUs g1 leaves idle and removes one kernel boundary.
__global__ __launch_bounds__(256) void gemm_g1_preds(
        const __hip_bfloat16* __restrict__ x1full,
        const __hip_bfloat16* __restrict__ W1cat,
        float* __restrict__ g_part, size_t gstride,
        const __hip_bfloat16* __restrict__ Wfc,
        float* __restrict__ pred_out,            // null at t==0
        const float* __restrict__ bfc,
        const int* __restrict__ dec_len, int tprev) {
    __shared__ __align__(16) short As[BM][LDS_K];
    __shared__ __align__(16) short Wsm[BN][LDS_K];
    int idx = blockIdx.x;
    if (idx < 512) {
        int bx = idx & 63, bz = idx >> 6;
        gemm_core<0>(As, Wsm, 0, bx * BN, bz * 640,
                     x1full, 5120, W1cat, 5120,
                     g_part + (size_t)bz * gstride, 4096,
                     4096, 640, nullptr, nullptr, 0);
    } else {
        if (!pred_out) return;
        gemm_core<1>(As, Wsm, 0, (idx - 512) * BN, 0,
                     x1full, 5120, Wfc, DD,
                     pred_out, TT * VV,
                     VV, DD, bfc, dec_len, tprev);
    }
}

// ---------------- LSTM pointwise: sum 8 split-K partials + biases ----------------
// Optionally gathers next step's embedding into x1full emb slot (lstm2 only).
__global__ void lstm_kernel(const float* __restrict__ gpart, size_t pstride,
                            const float* __restrict__ bih, const float* __restrict__ bhh,
                            float* __restrict__ c,
                            __hip_bfloat16* __restrict__ hs1, int st1,
                            __hip_bfloat16* __restrict__ hs2, int st2,
                            const int* __restrict__ dec_len, int t,
                            const float* __restrict__ embF,
                            const int* __restrict__ caps,
                            const int* __restrict__ sort_ind,
                            __hip_bfloat16* __restrict__ embdst, int tnext) {
    int idx = blockIdx.x * 256 + threadIdx.x;   // B*DD threads
    int b = idx >> 10;
    int d = idx & 1023;
    bool act = t < dec_len[b];
    if (embdst && act) {   // rows active at t+1 are a subset of rows active at t
        int cap = caps[sort_ind[b] * LL + tnext];
        embdst[(size_t)b * 5120 + d] = __float2bfloat16(embF[(size_t)cap * EE + d]);
    }
    if (!act) return;
    float g[4];
#pragma unroll
    for (int gate = 0; gate < 4; ++gate) {
        size_t o = (size_t)b * 4096 + gate * 1024 + d;
        float s = bih[gate * 1024 + d] + bhh[gate * 1024 + d];
#pragma unroll
        for (int z = 0; z < 8; ++z) s += gpart[z * pstride + o];
        g[gate] = s;
    }
    float si = 1.f / (1.f + expf(-g[0]));
    float sf = 1.f / (1.f + expf(-g[1]));
    float so = 1.f / (1.f + expf(-g[3]));
    float cc = sf * c[idx] + si * tanhf(g[2]);
    float hh = so * tanhf(cc);
    c[idx] = cc;
    __hip_bfloat16 hb = __float2bfloat16(hh);
    hs1[(size_t)b * st1 + d] = hb;
    hs2[(size_t)b * st2 + d] = hb;
}

// ---------------- fused attention: av-reduce + score + softmax + awe (one block per b) ----
// Replaces att2sum + score + awe kernels (2 fewer kernel boundaries per step).
// av goes through a per-b global scratch row (written+read by the same block; same-CU
// store->load after __syncthreads is coherent) so the score phase keeps the proven
// coalesced 64B/lane access pattern instead of a 32-way-bank-conflicted LDS stride.
__global__ __launch_bounds__(256) void att_fused(
        const float* __restrict__ p, size_t pstride,   // 16 x (B,AA) partials
        const float* __restrict__ bf_,
        const float* __restrict__ bd_,
        float* __restrict__ av_g,                      // (B,AA) scratch
        const __hip_bfloat16* __restrict__ att1,       // (B*NN, AA) bf16
        const float* __restrict__ Wa,                  // (AA)
        const __hip_bfloat16* __restrict__ feats,      // (B, NN, FF) sorted bf16
        __hip_bfloat16* __restrict__ x2full) {         // awe slot, row stride 4096
    int b = blockIdx.x;
    int tid = threadIdx.x;
    __shared__ float esh[NN];
    __shared__ float alpha[NN];

    // phase 1: av = bf + bd + sum_z partials  (coalesced, 4 elems/thread)
#pragma unroll
    for (int rep = 0; rep < 4; ++rep) {
        int a = rep * 256 + tid;
        size_t o = (size_t)b * AA + a;
        float s = bf_[a] + bd_[a];
#pragma unroll
        for (int z = 0; z < 16; ++z) s += p[z * pstride + o];
        av_g[o] = s;
    }
    __syncthreads();

    // phase 2: scores, wave per n (4 waves, 9 n each)
    int wv = tid >> 6, lane = tid & 63;
    const float* avp = av_g + (size_t)b * AA + lane * 16;
    const float* wap = Wa + lane * 16;
    for (int n = wv; n < NN; n += 4) {
        const __hip_bfloat16* a1 = att1 + ((size_t)b * NN + n) * AA + lane * 16;
        float pacc = 0.f;
#pragma unroll
        for (int h = 0; h < 2; ++h) {
            short8 a8 = *(const short8*)(a1 + h * 8);
            floatx4 v0 = *(const floatx4*)(avp + h * 8);
            floatx4 v1 = *(const floatx4*)(avp + h * 8 + 4);
            floatx4 w0 = *(const floatx4*)(wap + h * 8);
            floatx4 w1 = *(const floatx4*)(wap + h * 8 + 4);
            float af[8];
#pragma unroll
            for (int q = 0; q < 8; ++q) {
                union { short s; __hip_bfloat16 b; } u; u.s = a8[q];
                af[q] = __bfloat162float(u.b);
            }
#pragma unroll
            for (int q = 0; q < 4; ++q) {
                pacc += fmaxf(af[q] + v0[q], 0.f) * w0[q];
                pacc += fmaxf(af[4 + q] + v1[q], 0.f) * w1[q];
            }
        }
        for (int off = 32; off; off >>= 1) pacc += __shfl_down(pacc, off);
        if (lane == 0) esh[n] = pacc;
    }
    __syncthreads();

    // phase 3: softmax over NN=36 on wave 0
    if (tid < 64) {
        float ev = (tid < NN) ? esh[tid] : -INFINITY;
        float m = ev;
        for (int off = 32; off; off >>= 1) m = fmaxf(m, __shfl_down(m, off));
        m = __shfl(m, 0);
        float ex = (tid < NN) ? expf(ev - m) : 0.f;
        float s = ex;
        for (int off = 32; off; off >>= 1) s += __shfl_down(s, off);
        s = __shfl(s, 0);
        if (tid < NN) alpha[tid] = ex / s;
    }
    __syncthreads();

    // phase 4: awe — 8 outputs per thread (256*8 = 2048), coalesced 16B/lane
    const __hip_bfloat16* src = feats + (size_t)b * (NN * FF) + tid * 8;
    float s[8] = {0.f, 0.f, 0.f, 0.f, 0.f, 0.f, 0.f, 0.f};
#pragma unroll
    for (int n = 0; n < NN; ++n) {
        short8 v = *(const short8*)(src + (size_t)n * FF);
        float al = alpha[n];
#pragma unroll
        for (int q = 0; q < 8; ++q) {
            union { short s_; __hip_bfloat16 b_; } u; u.s_ = v[q];
            s[q] += al * __bfloat162float(u.b_);
        }
    }
    short8 o8;
#pragma unroll
    for (int q = 0; q < 8; ++q) {
        union { short s_; __hip_bfloat16 b_; } u; u.b_ = __float2bfloat16(s[q]);
        o8[q] = u.s_;
    }
    *(short8*)(x2full + (size_t)b * 4096 + tid * 8) = o8;
}

// ---------------- host launcher ----------------
extern "C" void kernel_launch(void* const* d_in, const int* in_sizes, int n_in,
                              void* d_out, int out_size, void* d_ws, size_t ws_size,
                              hipStream_t stream) {
    const float* img     = (const float*)d_in[0];
    const int*   caps    = (const int*)d_in[1];
    const int*   cap_len = (const int*)d_in[2];
    const float* emb     = (const float*)d_in[3];
    const float* W1_ih   = (const float*)d_in[4];
    const float* W1_hh   = (const float*)d_in[5];
    const float* b1_ih   = (const float*)d_in[6];
    const float* b1_hh   = (const float*)d_in[7];
    const float* W2_ih   = (const float*)d_in[8];
    const float* W2_hh   = (const float*)d_in[9];
    const float* b2_ih   = (const float*)d_in[10];
    const float* b2_hh   = (const float*)d_in[11];
    const float* Wf      = (const float*)d_in[12];
    const float* bf      = (const float*)d_in[13];
    const float* Wd      = (const float*)d_in[14];
    const float* bd      = (const float*)d_in[15];
    const float* Wa      = (const float*)d_in[16];
    // d_in[17] = ba: softmax shift-invariant, unused
    const float* Wfc     = (const float*)d_in[18];
    const float* bfc     = (const float*)d_in[19];
    float* out = (float*)d_out;
    (void)in_sizes; (void)n_in; (void)out_size; (void)ws_size;

    char* ws = (char*)d_ws;
    size_t off = 0;
    auto alloc = [&](size_t bytes) -> void* {
        void* p = ws + off;
        off += (bytes + 255) & ~(size_t)255;
        return p;
    };
    int* sort_ind = (int*)alloc(B * sizeof(int));
    int* dec_len  = (int*)alloc(B * sizeof(int));
    __hip_bfloat16* W1cat    = (__hip_bfloat16*)alloc((size_t)4096 * 5120 * 2);
    __hip_bfloat16* W2cat    = (__hip_bfloat16*)alloc((size_t)4096 * 4096 * 2);
    __hip_bfloat16* Wd_bf    = (__hip_bfloat16*)alloc((size_t)AA * DD * 2);
    __hip_bfloat16* Wfc_bf   = (__hip_bfloat16*)alloc((size_t)VV * DD * 2);
    __hip_bfloat16* Wf_bf    = (__hip_bfloat16*)alloc((size_t)AA * FF * 2);
    __hip_bfloat16* feats_bf = (__hip_bfloat16*)alloc((size_t)B * NN * FF * 2);
    __hip_bfloat16* att1_bf  = (__hip_bfloat16*)alloc((size_t)B * NN * AA * 2);
    float* g_part    = (float*)alloc((size_t)8 * B * 4096 * 4);
    float* att2_part = (float*)alloc((size_t)16 * B * AA * 4);
    float* av        = (float*)alloc((size_t)B * AA * 4);
    __hip_bfloat16* x1full = (__hip_bfloat16*)alloc((size_t)B * 5120 * 2); // [h2|fm|emb|h1]
    __hip_bfloat16* x2full = (__hip_bfloat16*)alloc((size_t)B * 4096 * 2); // [awe|h1|h2]
    float* c1 = (float*)alloc((size_t)B * DD * 4);
    float* c2 = (float*)alloc((size_t)B * DD * 4);

    // ---- setup ----
    sort_kernel<<<1, B, 0, stream>>>(cap_len, sort_ind, dec_len);
    pack_w1_kernel<<<(4096 * 5120) / 256, 256, 0, stream>>>(W1_ih, W1_hh, W1cat);
    pack_w2_kernel<<<(4096 * 4096) / 256, 256, 0, stream>>>(W2_ih, W2_hh, W2cat);
    convert_kernel<<<(AA * DD) / 256, 256, 0, stream>>>(Wd, Wd_bf, AA * DD);
    convert_kernel<<<(VV * DD + 255) / 256, 256, 0, stream>>>(Wfc, Wfc_bf, VV * DD);
    convert_kernel<<<(AA * FF) / 256, 256, 0, stream>>>(Wf, Wf_bf, AA * FF);
    feats_bf_kernel<<<(B * NN * FF) / 256, 256, 0, stream>>>(img, sort_ind, feats_bf);
    hipMemsetAsync(x1full, 0, (size_t)B * 5120 * 2, stream);
    hipMemsetAsync(x2full, 0, (size_t)B * 4096 * 2, stream);
    hipMemsetAsync(c1, 0, (size_t)B * DD * 4, stream);
    hipMemsetAsync(c2, 0, (size_t)B * DD * 4, stream);
    fm_kernel<<<(B * FF) / 256, 256, 0, stream>>>(img, sort_ind, x1full);
    emb_gather_kernel<<<(B * EE) / 256, 256, 0, stream>>>(emb, caps, sort_ind, 0, x1full);

    // att1 = feats_bf @ Wf^T (bf16 out; bf bias folded into att_fused)
    gemm_bf16<2><<<dim3(AA / BN, (B * NN) / BM, 1), 256, 0, stream>>>(
        feats_bf, FF, Wf_bf, FF, (float*)att1_bf, AA, 0, AA, FF, nullptr, nullptr, 0);

    const size_t gstride = (size_t)B * 4096;
    const size_t astride = (size_t)B * AA;

    for (int t = 0; t < TT; ++t) {
        // g1(t) = [h2|fm|emb|h1] @ [W1_ih|W1_hh]^T (split-K 8)  merged with preds(t-1)
        gemm_g1_preds<<<512 + (VV + BN - 1) / BN, 256, 0, stream>>>(
            x1full, W1cat, g_part, gstride,
            Wfc_bf, (t > 0) ? (out + (size_t)(t - 1) * VV) : nullptr,
            bfc, dec_len, t - 1);
        lstm_kernel<<<(B * DD) / 256, 256, 0, stream>>>(
            g_part, gstride, b1_ih, b1_hh, c1,
            x1full + 4096, 5120, x2full + 2048, 4096, dec_len, t,
            nullptr, nullptr, nullptr, nullptr, 0);

        // att2 partials = h1 @ Wd^T : K=1024, split-K 16 (Kc=64)
        gemm_bf16<0><<<dim3(AA / BN, 1, 16), 256, 0, stream>>>(
            x2full + 2048, 4096, Wd_bf, DD, att2_part, AA, astride, AA, 64,
            nullptr, nullptr, 0);

        // fused: av-reduce + score + softmax + awe
        att_fused<<<B, 256, 0, stream>>>(att2_part, astride, bf, bd, av,
                                         att1_bf, Wa, feats_bf, x2full);

        // g2 = [awe|h1|h2] @ [W2_ih|W2_hh]^T : K=4096, split-K 8 (Kc=512)
        gemm_bf16<0><<<dim3(4096 / BN, 1, 8), 256, 0, stream>>>(
            x2full, 4096, W2cat, 4096, g_part, 4096, gstride, 4096, 512,
            nullptr, nullptr, 0);
        lstm_kernel<<<(B * DD) / 256, 256, 0, stream>>>(
            g_part, gstride, b2_ih, b2_hh, c2,
            x1full + 0, 5120, x2full + 3072, 4096, dec_len, t,
            emb, caps, sort_ind, (t + 1 < TT) ? (x1full + 3072) : nullptr, t + 1);
    }

    // final preds for t = TT-1 (no next-step g1 to merge with)
    gemm_bf16<1><<<dim3((VV + BN - 1) / BN, 1, 1), 256, 0, stream>>>(
        x1full, 5120, Wfc_bf, DD, out + (size_t)(TT - 1) * VV, TT * VV, 0, VV, DD,
        bfc, dec_len, TT - 1);
}